// Round 12
// baseline (200.147 us; speedup 1.0000x reference)
//
#include <hip/hip_runtime.h>
#include <hip/hip_bf16.h>
#include <cstdint>

#define IN_CH 512
#define OUT_CH 512
#define STYLE_DIM 512
#define BATCH 8
#define HW 64

typedef __bf16 bf16x8 __attribute__((ext_vector_type(8)));
typedef float f32x16 __attribute__((ext_vector_type(16)));

__device__ __forceinline__ void gload_lds16(const void* g, void* l) {
  __builtin_amdgcn_global_load_lds(
      (const __attribute__((address_space(1))) unsigned int*)g,
      (__attribute__((address_space(3))) unsigned int*)l,
      16, 0, 0);
}

#define WAITV(N) asm volatile("s_waitcnt vmcnt(" #N ")" ::: "memory")
#define BARRIER() do { asm volatile("" ::: "memory"); __builtin_amdgcn_s_barrier(); \
                       asm volatile("" ::: "memory"); } while (0)

// ---------------- prepass 1: s[b][ic] ----------------
__global__ void k_style(const float* __restrict__ style, const float* __restrict__ modw,
                        const float* __restrict__ modb, float* __restrict__ s_out) {
  __shared__ float st[BATCH * STYLE_DIM];
  const int tid = threadIdx.x;
  for (int i = tid; i < BATCH * STYLE_DIM; i += 256) st[i] = style[i];
  __syncthreads();
  const int ic = blockIdx.x * 4 + (tid >> 6);
  const int l = tid & 63;
  const float* mr = modw + (size_t)ic * STYLE_DIM + l * 8;
  float m[8];
  #pragma unroll
  for (int j = 0; j < 8; ++j) m[j] = mr[j];
  float accs[8];
  #pragma unroll
  for (int b = 0; b < 8; ++b) {
    const float* sb = st + b * STYLE_DIM + l * 8;
    float a = 0.f;
    #pragma unroll
    for (int j = 0; j < 8; ++j) a += m[j] * sb[j];
    accs[b] = a;
  }
  #pragma unroll
  for (int off = 32; off; off >>= 1) {
    #pragma unroll
    for (int b = 0; b < 8; ++b) accs[b] += __shfl_down(accs[b], off, 64);
  }
  if (l == 0) {
    #pragma unroll
    for (int b = 0; b < 8; ++b)
      s_out[b * IN_CH + ic] = accs[b] * 0.04419417382415922f + modb[ic];
  }
}

// ---------------- prepass 2: wsq + bf16 W (LINEAR layout; swizzle now lives in k_conv) ---
__global__ void k_wprep(const float* __restrict__ w, float* __restrict__ wsq,
                        __bf16* __restrict__ wb) {
  const int idx = blockIdx.x * 256 + threadIdx.x;
  const int oc = idx >> 9, ic = idx & 511;
  const float* p = w + ((size_t)oc * IN_CH + ic) * 9;
  float sum = 0.f;
  #pragma unroll
  for (int t = 0; t < 9; ++t) {
    float v = p[t];
    sum += v * v;
    wb[((size_t)(t * OUT_CH) + oc) * IN_CH + ic] = (__bf16)v;
  }
  wsq[oc * IN_CH + ic] = sum;
}

// ---------------- prepass 3: demod scale ----------------
__global__ void k_demod(const float* __restrict__ s, const float* __restrict__ wsq,
                        float* __restrict__ scale) {
  const int oc = blockIdx.x;
  const int l = threadIdx.x;
  const float* wr = wsq + (size_t)oc * IN_CH + l * 8;
  float w8[8];
  #pragma unroll
  for (int j = 0; j < 8; ++j) w8[j] = wr[j];
  #pragma unroll
  for (int b = 0; b < 8; ++b) {
    const float* sb = s + b * IN_CH + l * 8;
    float acc = 0.f;
    #pragma unroll
    for (int j = 0; j < 8; ++j) { float sv = sb[j]; acc += sv * sv * w8[j]; }
    #pragma unroll
    for (int off = 32; off; off >>= 1) acc += __shfl_down(acc, off, 64);
    if (l == 0)
      scale[b * OUT_CH + oc] =
          rsqrtf(acc * (1.0f / 4608.0f) + 1e-8f) * 0.014731391274719732f;
  }
}

// ---------------- prepass 4: xg[b][ug][y][x][8] = bf16(x * s) ----------------
__global__ void k_xprep(const float* __restrict__ x, const float* __restrict__ s,
                        __bf16* __restrict__ xg) {
  const int b = blockIdx.x >> 6, y = blockIdx.x & 63;
  const int w = threadIdx.x >> 6, lane = threadIdx.x & 63;
  const float* sr = s + b * IN_CH;
  #pragma unroll
  for (int it = 0; it < 8; ++it) {
    const int ug = it * 8 + w;
    bf16x8 pk;
    #pragma unroll
    for (int j = 0; j < 8; ++j) {
      const int ic = ug * 8 + j;
      pk[j] = (__bf16)(x[(((size_t)(b * IN_CH) + ic) * HW + y) * HW + lane] * sr[ic]);
    }
    *(bf16x8*)(xg + ((((size_t)(b * 64 + ug) * HW + y) * HW + lane) * 8)) = pk;
  }
}

// ---------------- main conv: conflict-free 256B-stripe LDS layout + ks stagger -----------
// Layout: (row R, slot s) -> byte (R>>1)*256 + ((R+2s)&15)*16. Any 32-consecutive-row
// read at fixed slot hits all 16 positions 2x -> 8 accesses/bank = conflict-free.
// LDS dest stays linear (unit u = i*512+tid); the permutation lives in the per-lane
// GLOBAL source (inverse map R=2(u>>4)+(u&1), s=((u&15)>>1-(u>>4))&7). Halo/OOR X units
// source from a zeroed global page. Waves stagger ks start (kord=wid&3) to desync
// port-bursts from MFMA-bursts.
__global__ __launch_bounds__(512, 2) void k_conv(
    const __bf16* __restrict__ Wg,   // [9][512][512] linear
    const __bf16* __restrict__ Xg,   // [8][64 ug][64 y][64 x][8]
    const float* __restrict__ scale, // [8][512] = demod*cs
    const __bf16* __restrict__ zpg,  // 256 B of zeros (halo source)
    float* __restrict__ out)         // [8][512][64][64]
{
  __shared__ __attribute__((aligned(16))) __bf16 Xs[3584 * 8];     // 57344 B (396 rows+pad)
  __shared__ __attribute__((aligned(16))) __bf16 Wl[3][2048 * 8];  // 98304 B

  const int tid = threadIdx.x;
  const int lane = tid & 63;
  const int wid = tid >> 6;
  const int wm = wid >> 2;      // oc half
  const int wn = wid & 3;       // image row within tile
  const int ln31 = lane & 31;
  const int laneK = lane >> 5;
  const int kord = wid & 3;     // per-wave ks-phase stagger

  const int bid0 = blockIdx.x;
  const int bid = (bid0 & 7) * 32 + (bid0 >> 3);   // XCD-chunked swizzle
  const int octile = bid & 1;
  const int ptile = (bid >> 1) & 15;
  const int b = bid >> 5;
  const int oc0 = octile * 256;
  const int r0 = ptile * 4;

  auto stage_w = [&](int chunkv, int tapv, int bsel) {  // 4 gload16/thread = 32 KB
    #pragma unroll
    for (int i = 0; i < 4; ++i) {
      const int u = i * 512 + tid;          // linear LDS unit
      const int j = u >> 4, p = u & 15;
      const int row = 2 * j + (p & 1);      // inverse stripe map
      const int s = ((p >> 1) - j) & 7;
      gload_lds16(Wg + (((size_t)(tapv * OUT_CH) + oc0 + row) * IN_CH + chunkv * 64 + s * 8),
                  (void*)((char*)Wl[bsel] + u * 16));
    }
  };
  auto stage_x = [&](int chunkv) {   // ALWAYS 7 gload16/thread (fixed vmcnt bookkeeping)
    #pragma unroll
    for (int i = 0; i < 7; ++i) {
      const int u = i * 512 + tid;
      const int j = u >> 4, p = u & 15;
      const int R = 2 * j + (p & 1);        // logical row = xrow*66 + col
      const int s = ((p >> 1) - j) & 7;
      const int xrow = (int)((unsigned)R / 66u);
      const int col = R - 66 * xrow;
      const int y = r0 - 1 + xrow;
      const bool ok = (col >= 1) & (col <= 64) & (y >= 0) & (y < HW);
      const __bf16* src = ok
          ? Xg + ((((size_t)(b * 64 + chunkv * 8 + s) * HW + y) * HW + (col - 1)) * 8)
          : zpg;                            // halo/OOR -> zeros (conv padding)
      gload_lds16(src, (void*)((char*)Xs + u * 16));
    }
  };

  // prologue: no LDS zero-init needed (every unit staged each chunk, halos from zpg)
  stage_x(0);               // X0(7)
  stage_w(0, 0, 0);         // +W0(4)
  stage_w(0, 1, 1);         // +W1(4) -> first tap's WAITV(4) drains X0+W0, keeps W1

  // ---- per-lane read addressing (conflict-free layout), all loop-invariant ----
  const int keyA = ln31 + 2 * laneK + 4 * kord;
  int aoff8[4];
  #pragma unroll
  for (int ks = 0; ks < 4; ++ks) aoff8[ks] = ((keyA + 4 * ks) & 15) * 8;  // elements
  const __bf16* __restrict__ ab0 = Wl[0] + (64 * wm + (ln31 >> 1)) * 128;
  const __bf16* __restrict__ ab1 = Wl[1] + (64 * wm + (ln31 >> 1)) * 128;
  const __bf16* __restrict__ ab2 = Wl[2] + (64 * wm + (ln31 >> 1)) * 128;
  const int RB = wn * 66 + ln31;            // B logical row base (+ tap const)
  const int kB0 = RB + 2 * laneK + 4 * kord;

  f32x16 acc[4][2] = {};

  // per-tap body; T compile-time, c runtime chunk index
#define TAPBODY(T) { \
    if ((T) == 8 && c == 7) { WAITV(0); } else { WAITV(4); } \
    BARRIER(); \
    const __bf16* __restrict__ abase = ((T) % 3 == 0) ? ab0 : ((T) % 3 == 1) ? ab1 : ab2; \
    const int Rt = RB + ((T) / 3) * 66 + ((T) % 3); \
    const int kBt = kB0 + ((T) / 3) * 66 + ((T) % 3); \
    const __bf16* __restrict__ xbase = Xs + (Rt >> 1) * 128; \
    _Pragma("unroll") \
    for (int ks = 0; ks < 4; ++ks) { \
      const int bp = ((kBt + 4 * ks) & 15) * 8; \
      bf16x8 av[4], bv[2]; \
      _Pragma("unroll") \
      for (int mf = 0; mf < 4; ++mf) av[mf] = *(const bf16x8*)(abase + mf * 2048 + aoff8[ks]); \
      bv[0] = *(const bf16x8*)(xbase + bp); \
      bv[1] = *(const bf16x8*)(xbase + 2048 + bp); \
      __builtin_amdgcn_s_setprio(1); \
      _Pragma("unroll") \
      for (int mf = 0; mf < 4; ++mf) { \
        acc[mf][0] = __builtin_amdgcn_mfma_f32_32x32x16_bf16(av[mf], bv[0], acc[mf][0], 0, 0, 0); \
        acc[mf][1] = __builtin_amdgcn_mfma_f32_32x32x16_bf16(av[mf], bv[1], acc[mf][1], 0, 0, 0); \
      } \
      __builtin_amdgcn_s_setprio(0); \
    } \
    if ((T) == 8) { \
      if (c < 7) { BARRIER(); stage_x(c + 1); stage_w(c + 1, 1, 1); } \
    } else if ((T) <= 6) { \
      stage_w(c, (T) + 2, ((T) + 2) % 3); \
    } else { /* T == 7 */ \
      if (c < 7) stage_w(c + 1, 0, 0); \
    } \
  }

  #pragma unroll 1
  for (int c = 0; c < 8; ++c) {
    TAPBODY(0) TAPBODY(1) TAPBODY(2)
    TAPBODY(3) TAPBODY(4) TAPBODY(5)
    TAPBODY(6) TAPBODY(7) TAPBODY(8)
  }

  // epilogue: out = acc * (demod*cs), NCHW
  const int y = r0 + wn;
  #pragma unroll
  for (int mf = 0; mf < 4; ++mf) {
    #pragma unroll
    for (int reg = 0; reg < 16; ++reg) {
      const int rowid = (reg & 3) + 8 * (reg >> 2) + 4 * laneK;
      const int oc = oc0 + 128 * wm + 32 * mf + rowid;
      const float sc = scale[b * OUT_CH + oc];
      float* op = out + (((size_t)(b * OUT_CH + oc) * HW + y) * HW) + ln31;
      op[0] = acc[mf][0][reg] * sc;
      op[32] = acc[mf][1][reg] * sc;
    }
  }
}

// ---------------- launcher ---------------------------------------------------------------
extern "C" void kernel_launch(void* const* d_in, const int* in_sizes, int n_in,
                              void* d_out, int out_size, void* d_ws, size_t ws_size,
                              hipStream_t stream) {
  const float* x      = (const float*)d_in[0];
  const float* style  = (const float*)d_in[1];
  const float* weight = (const float*)d_in[2];
  const float* modw   = (const float*)d_in[3];
  const float* modb   = (const float*)d_in[4];
  float* out = (float*)d_out;

  char* ws = (char*)d_ws;
  float*  s_buf = (float*)(ws + 0);                        // 16 KB
  float*  scale = (float*)(ws + 16384);                    // 16 KB
  __bf16* zpg   = (__bf16*)(ws + 32768);                   // 4 KB zero page
  float*  wsq   = (float*)(ws + 36864);                    // 1 MB
  __bf16* wb    = (__bf16*)(ws + 36864 + 1048576);         // 4.72 MB
  __bf16* xg    = (__bf16*)(ws + 36864 + 1048576 + 9 * OUT_CH * IN_CH * 2);  // 33.5 MB

  hipMemsetAsync(zpg, 0, 4096, stream);
  k_style<<<128, 256, 0, stream>>>(style, modw, modb, s_buf);
  k_wprep<<<1024, 256, 0, stream>>>(weight, wsq, wb);
  k_demod<<<512, 64, 0, stream>>>(s_buf, wsq, scale);
  k_xprep<<<BATCH * HW, 512, 0, stream>>>(x, s_buf, xg);
  k_conv<<<256, 512, 0, stream>>>(wb, xg, scale, zpg, out);
}

// Round 13
// 167.187 us; speedup vs baseline: 1.1971x; 1.1971x over previous
//
#include <hip/hip_runtime.h>
#include <hip/hip_bf16.h>
#include <cstdint>

#define IN_CH 512
#define OUT_CH 512
#define STYLE_DIM 512
#define BATCH 8
#define HW 64

typedef __bf16 bf16x8 __attribute__((ext_vector_type(8)));
typedef float f32x16 __attribute__((ext_vector_type(16)));

__device__ __forceinline__ void gload_lds16(const void* g, void* l) {
  __builtin_amdgcn_global_load_lds(
      (const __attribute__((address_space(1))) unsigned int*)g,
      (__attribute__((address_space(3))) unsigned int*)l,
      16, 0, 0);
}

#define WAITV(N) asm volatile("s_waitcnt vmcnt(" #N ")" ::: "memory")
#define BARRIER() do { asm volatile("" ::: "memory"); __builtin_amdgcn_s_barrier(); \
                       asm volatile("" ::: "memory"); } while (0)

// ---------------- prepass 1: s[b][ic] ----------------
__global__ void k_style(const float* __restrict__ style, const float* __restrict__ modw,
                        const float* __restrict__ modb, float* __restrict__ s_out) {
  __shared__ float st[BATCH * STYLE_DIM];
  const int tid = threadIdx.x;
  for (int i = tid; i < BATCH * STYLE_DIM; i += 256) st[i] = style[i];
  __syncthreads();
  const int ic = blockIdx.x * 4 + (tid >> 6);
  const int l = tid & 63;
  const float* mr = modw + (size_t)ic * STYLE_DIM + l * 8;
  float m[8];
  #pragma unroll
  for (int j = 0; j < 8; ++j) m[j] = mr[j];
  float accs[8];
  #pragma unroll
  for (int b = 0; b < 8; ++b) {
    const float* sb = st + b * STYLE_DIM + l * 8;
    float a = 0.f;
    #pragma unroll
    for (int j = 0; j < 8; ++j) a += m[j] * sb[j];
    accs[b] = a;
  }
  #pragma unroll
  for (int off = 32; off; off >>= 1) {
    #pragma unroll
    for (int b = 0; b < 8; ++b) accs[b] += __shfl_down(accs[b], off, 64);
  }
  if (l == 0) {
    #pragma unroll
    for (int b = 0; b < 8; ++b)
      s_out[b * IN_CH + ic] = accs[b] * 0.04419417382415922f + modb[ic];
  }
}

// ---------------- prepass 2: wsq + W in stager-linear stripe order -----------------------
// wgp[tap][chunk][octile][2048 units of 16B]; unit u=(j,p): row R=2j+(p&1) (oc-local),
// slot s=((p>>1)-j)&7 (8 bf16 of ic). Equivalent read algebra: pos=(R+2s)&15.
__global__ void k_wprep(const float* __restrict__ w, float* __restrict__ wsq,
                        __bf16* __restrict__ wgp) {
  const int idx = blockIdx.x * 256 + threadIdx.x;  // 262144
  const int oc = idx >> 9, ic = idx & 511;
  const int octile = oc >> 8, R = oc & 255, j = R >> 1;
  const int chunk = ic >> 6, sslot = (ic >> 3) & 7, e = ic & 7;
  const int p = 2 * ((sslot + j) & 7) + (R & 1);
  const int u = j * 16 + p;
  const float* pw = w + ((size_t)oc * IN_CH + ic) * 9;
  float sum = 0.f;
  #pragma unroll
  for (int t = 0; t < 9; ++t) {
    float v = pw[t];
    sum += v * v;
    wgp[((size_t)((t * 8 + chunk) * 2 + octile) * 2048 + u) * 8 + e] = (__bf16)v;
  }
  wsq[oc * IN_CH + ic] = sum;
}

// ---------------- prepass 3: demod scale ----------------
__global__ void k_demod(const float* __restrict__ s, const float* __restrict__ wsq,
                        float* __restrict__ scale) {
  const int oc = blockIdx.x;
  const int l = threadIdx.x;
  const float* wr = wsq + (size_t)oc * IN_CH + l * 8;
  float w8[8];
  #pragma unroll
  for (int j = 0; j < 8; ++j) w8[j] = wr[j];
  #pragma unroll
  for (int b = 0; b < 8; ++b) {
    const float* sb = s + b * IN_CH + l * 8;
    float acc = 0.f;
    #pragma unroll
    for (int j = 0; j < 8; ++j) { float sv = sb[j]; acc += sv * sv * w8[j]; }
    #pragma unroll
    for (int off = 32; off; off >>= 1) acc += __shfl_down(acc, off, 64);
    if (l == 0)
      scale[b * OUT_CH + oc] =
          rsqrtf(acc * (1.0f / 4608.0f) + 1e-8f) * 0.014731391274719732f;
  }
}

// ---------------- prepass 4: xgp[b][y][chunk][528 units] (halo cols baked as zeros) ------
// unit u=(c,p): col=2c+(p&1) (0..65, data x=col-1), slot s=((p>>1)-c)&7. Read:
// pos=(col&1)+2((s+c)&7). Col-local key -> layout is ptile-independent.
__global__ void k_xprep(const float* __restrict__ x, const float* __restrict__ s,
                        __bf16* __restrict__ xgp) {
  const int b = blockIdx.x >> 6, y = blockIdx.x & 63;   // 512 blocks x 512 thr
  const int t = threadIdx.x;
  const int xcol = t & 63;          // image x, data col = xcol+1
  const int g0 = t >> 6;            // 0..7
  const float* sr = s + b * IN_CH;
  const size_t rowbase = ((size_t)(b * 64 + y)) * 8 * 528;
  #pragma unroll
  for (int i = 0; i < 8; ++i) {
    const int g = i * 8 + g0;       // chunk*8 + slot
    bf16x8 pk;
    #pragma unroll
    for (int e = 0; e < 8; ++e) {
      const int ic = g * 8 + e;
      pk[e] = (__bf16)(x[(((size_t)(b * IN_CH) + ic) * HW + y) * HW + xcol] * sr[ic]);
    }
    const int col = xcol + 1, c = col >> 1;
    const int p = 2 * (((g & 7) + c) & 7) + (col & 1);
    const int u = c * 16 + p;
    *(bf16x8*)(xgp + (rowbase + (size_t)(g >> 3) * 528 + u) * 8) = pk;
  }
  if (t < 128) {                    // halo cols 0 and 65 -> zeros
    const int col = (t & 1) * 65, g = t >> 1;
    const int c = col >> 1;
    const int p = 2 * (((g & 7) + c) & 7) + (col & 1);
    const int u = c * 16 + p;
    bf16x8 z = {};
    *(bf16x8*)(xgp + (rowbase + (size_t)(g >> 3) * 528 + u) * 8) = z;
  }
}

// ---------------- main conv: r11 schedule + conflict-free stripe LDS, coalesced staging --
// Stagers read wgp/xgp LINEARLY (unit u = i*512+tid -> u*16B both sides): r11's coalesced
// VMEM. Conflict-free reads: A pos=(ln31+4ks+2laneK)&15 (measured 0 conflicts, r12);
// B pos=(col&1)+2((2ks+laneK+c)&7); nf=+32 cols = +4096B, mf=+32 rows = +4096B.
__global__ __launch_bounds__(512, 2) void k_conv(
    const __bf16* __restrict__ Wgp,  // [9][8][2][2048*8]
    const __bf16* __restrict__ Xgp,  // [8][64][8][528*8]
    const float* __restrict__ scale, // [8][512] = demod*cs
    const __bf16* __restrict__ zpg,  // zeros (OOR-row source)
    float* __restrict__ out)         // [8][512][64][64]
{
  __shared__ __attribute__((aligned(16))) __bf16 Xs[3584 * 8];     // 57344 B (6x528u + pad)
  __shared__ __attribute__((aligned(16))) __bf16 Wl[3][2048 * 8];  // 98304 B

  const int tid = threadIdx.x;
  const int lane = tid & 63;
  const int wid = tid >> 6;
  const int wm = wid >> 2;      // oc half
  const int wn = wid & 3;       // image row within tile
  const int ln31 = lane & 31;
  const int laneK = lane >> 5;

  const int bid0 = blockIdx.x;
  const int bid = (bid0 & 7) * 32 + (bid0 >> 3);   // XCD-chunked swizzle
  const int octile = bid & 1;
  const int ptile = (bid >> 1) & 15;
  const int b = bid >> 5;
  const int r0 = ptile * 4;
  const int oc0 = octile * 256;

  auto stage_w = [&](int chunkv, int tapv, int bsel) {  // 4 units/thread, linear
    const __bf16* base = Wgp + (size_t)((tapv * 8 + chunkv) * 2 + octile) * (2048 * 8);
    #pragma unroll
    for (int i = 0; i < 4; ++i) {
      const int u = i * 512 + tid;
      gload_lds16(base + (size_t)u * 8, (void*)((char*)Wl[bsel] + u * 16));
    }
  };
  auto stage_x = [&](int chunkv) {   // 7 units/thread, linear within each row
    #pragma unroll
    for (int i = 0; i < 7; ++i) {
      const unsigned u = i * 512 + tid;
      const unsigned row = u / 528u;            // 0..6 (row 6 = pad)
      const unsigned rr = u - row * 528u;
      const int y = r0 - 1 + (int)row;
      const bool ok = (u < 3168u) & (y >= 0) & (y < HW);
      const __bf16* src = ok
          ? Xgp + (((size_t)(b * 64 + y) * 8 + chunkv) * 528 + rr) * 8
          : zpg;
      gload_lds16(src, (void*)((char*)Xs + u * 16));
    }
  };

  // prologue (no LDS zero-init: every unit staged; halos baked into xgp/zpg)
  stage_x(0);               // X0(7)
  stage_w(0, 0, 0);         // +W0(4)
  stage_w(0, 1, 1);         // +W1(4) -> first tap's WAITV(4) drains X0+W0, keeps W1

  // ---- read addressing (loop-invariant, const-indexed) ----
  int aoff8[4];
  #pragma unroll
  for (int ks = 0; ks < 4; ++ks) aoff8[ks] = ((ln31 + 4 * ks + 2 * laneK) & 15) * 8;
  int bele[3][4];
  #pragma unroll
  for (int dxi = 0; dxi < 3; ++dxi) {
    const int col = ln31 + dxi, c = col >> 1;
    #pragma unroll
    for (int ks = 0; ks < 4; ++ks) {
      const int pos = (col & 1) + 2 * ((2 * ks + laneK + c) & 7);
      bele[dxi][ks] = c * 128 + pos * 8;
    }
  }
  const __bf16* __restrict__ ab0 = Wl[0] + (64 * wm + (ln31 >> 1)) * 128;
  const __bf16* __restrict__ ab1 = Wl[1] + (64 * wm + (ln31 >> 1)) * 128;
  const __bf16* __restrict__ ab2 = Wl[2] + (64 * wm + (ln31 >> 1)) * 128;

  f32x16 acc[4][2] = {};

#define TAPBODY(T) { \
    if ((T) == 8 && c == 7) { WAITV(0); } else { WAITV(4); } \
    BARRIER(); \
    const __bf16* __restrict__ abase = ((T) % 3 == 0) ? ab0 : ((T) % 3 == 1) ? ab1 : ab2; \
    const __bf16* __restrict__ xbase = Xs + (wn + (T) / 3) * (33 * 128); \
    _Pragma("unroll") \
    for (int ks = 0; ks < 4; ++ks) { \
      const int ael = aoff8[ks]; \
      const int bel = bele[(T) % 3][ks]; \
      bf16x8 av[4], bv[2]; \
      _Pragma("unroll") \
      for (int mf = 0; mf < 4; ++mf) av[mf] = *(const bf16x8*)(abase + mf * 2048 + ael); \
      bv[0] = *(const bf16x8*)(xbase + bel); \
      bv[1] = *(const bf16x8*)(xbase + 2048 + bel); \
      __builtin_amdgcn_s_setprio(1); \
      _Pragma("unroll") \
      for (int mf = 0; mf < 4; ++mf) { \
        acc[mf][0] = __builtin_amdgcn_mfma_f32_32x32x16_bf16(av[mf], bv[0], acc[mf][0], 0, 0, 0); \
        acc[mf][1] = __builtin_amdgcn_mfma_f32_32x32x16_bf16(av[mf], bv[1], acc[mf][1], 0, 0, 0); \
      } \
      __builtin_amdgcn_s_setprio(0); \
    } \
    if ((T) == 8) { \
      if (c < 7) { BARRIER(); stage_x(c + 1); stage_w(c + 1, 1, 1); } \
    } else if ((T) <= 6) { \
      stage_w(c, (T) + 2, ((T) + 2) % 3); \
    } else { /* T == 7 */ \
      if (c < 7) stage_w(c + 1, 0, 0); \
    } \
  }

  #pragma unroll 1
  for (int c = 0; c < 8; ++c) {
    TAPBODY(0) TAPBODY(1) TAPBODY(2)
    TAPBODY(3) TAPBODY(4) TAPBODY(5)
    TAPBODY(6) TAPBODY(7) TAPBODY(8)
  }

  // epilogue: out = acc * (demod*cs), NCHW
  const int y = r0 + wn;
  #pragma unroll
  for (int mf = 0; mf < 4; ++mf) {
    #pragma unroll
    for (int reg = 0; reg < 16; ++reg) {
      const int rowid = (reg & 3) + 8 * (reg >> 2) + 4 * laneK;
      const int oc = oc0 + 128 * wm + 32 * mf + rowid;
      const float sc = scale[b * OUT_CH + oc];
      float* op = out + (((size_t)(b * OUT_CH + oc) * HW + y) * HW) + ln31;
      op[0] = acc[mf][0][reg] * sc;
      op[32] = acc[mf][1][reg] * sc;
    }
  }
}

// ---------------- launcher ---------------------------------------------------------------
extern "C" void kernel_launch(void* const* d_in, const int* in_sizes, int n_in,
                              void* d_out, int out_size, void* d_ws, size_t ws_size,
                              hipStream_t stream) {
  const float* x      = (const float*)d_in[0];
  const float* style  = (const float*)d_in[1];
  const float* weight = (const float*)d_in[2];
  const float* modw   = (const float*)d_in[3];
  const float* modb   = (const float*)d_in[4];
  float* out = (float*)d_out;

  char* ws = (char*)d_ws;
  float*  s_buf = (float*)(ws + 0);                        // 16 KB
  float*  scale = (float*)(ws + 16384);                    // 16 KB
  __bf16* zpg   = (__bf16*)(ws + 32768);                   // 16 KB zero page
  float*  wsq   = (float*)(ws + 49152);                    // 1 MB
  __bf16* wgp   = (__bf16*)(ws + 49152 + 1048576);         // 9*8*2*2048*8*2B = 4.72 MB
  __bf16* xgp   = (__bf16*)(ws + 49152 + 1048576 + 9 * 8 * 2 * 2048 * 8 * 2);  // 34.6 MB

  hipMemsetAsync(zpg, 0, 16384, stream);
  k_style<<<128, 256, 0, stream>>>(style, modw, modb, s_buf);
  k_wprep<<<1024, 256, 0, stream>>>(weight, wsq, wgp);
  k_demod<<<512, 64, 0, stream>>>(s_buf, wsq, scale);
  k_xprep<<<BATCH * HW, 512, 0, stream>>>(x, s_buf, xgp);
  k_conv<<<256, 512, 0, stream>>>(wgp, xgp, scale, zpg, out);
}

// Round 14
// 161.323 us; speedup vs baseline: 1.2407x; 1.0364x over previous
//
#include <hip/hip_runtime.h>
#include <hip/hip_bf16.h>
#include <cstdint>

#define IN_CH 512
#define OUT_CH 512
#define STYLE_DIM 512
#define BATCH 8
#define HW 64

typedef __bf16 bf16x8 __attribute__((ext_vector_type(8)));
typedef float f32x16 __attribute__((ext_vector_type(16)));

__device__ __forceinline__ void gload_lds16(const void* g, void* l) {
  __builtin_amdgcn_global_load_lds(
      (const __attribute__((address_space(1))) unsigned int*)g,
      (__attribute__((address_space(3))) unsigned int*)l,
      16, 0, 0);
}

#define WAITV(N) asm volatile("s_waitcnt vmcnt(" #N ")" ::: "memory")
#define BARRIER() do { asm volatile("" ::: "memory"); __builtin_amdgcn_s_barrier(); \
                       asm volatile("" ::: "memory"); } while (0)

// ---------------- fused prepass A: style-GEMM (blocks 0..127) | W prep (128..1151) ------
// wgp[tap][chunk][octile][2048 units of 16B]; unit u=(j,p): row R=2j+(p&1) (oc-local),
// slot s=((p>>1)-j)&7. Read algebra: pos=(R+2s)&15 -> conflict-free (measured 0, r12/r13).
__global__ void k_prepA(const float* __restrict__ style, const float* __restrict__ modw,
                        const float* __restrict__ modb, const float* __restrict__ w,
                        float* __restrict__ s_out, float* __restrict__ wsq,
                        __bf16* __restrict__ wgp) {
  const int tid = threadIdx.x;
  if (blockIdx.x < 128) {
    __shared__ float st[BATCH * STYLE_DIM];
    for (int i = tid; i < BATCH * STYLE_DIM; i += 256) st[i] = style[i];
    __syncthreads();
    const int ic = blockIdx.x * 4 + (tid >> 6);
    const int l = tid & 63;
    const float* mr = modw + (size_t)ic * STYLE_DIM + l * 8;
    float m[8];
    #pragma unroll
    for (int j = 0; j < 8; ++j) m[j] = mr[j];
    float accs[8];
    #pragma unroll
    for (int b = 0; b < 8; ++b) {
      const float* sb = st + b * STYLE_DIM + l * 8;
      float a = 0.f;
      #pragma unroll
      for (int j = 0; j < 8; ++j) a += m[j] * sb[j];
      accs[b] = a;
    }
    #pragma unroll
    for (int off = 32; off; off >>= 1) {
      #pragma unroll
      for (int b = 0; b < 8; ++b) accs[b] += __shfl_down(accs[b], off, 64);
    }
    if (l == 0) {
      #pragma unroll
      for (int b = 0; b < 8; ++b)
        s_out[b * IN_CH + ic] = accs[b] * 0.04419417382415922f + modb[ic];
    }
  } else {
    const int idx = (blockIdx.x - 128) * 256 + tid;  // 262144
    const int oc = idx >> 9, ic = idx & 511;
    const int octile = oc >> 8, R = oc & 255, j = R >> 1;
    const int chunk = ic >> 6, sslot = (ic >> 3) & 7, e = ic & 7;
    const int p = 2 * ((sslot + j) & 7) + (R & 1);
    const int u = j * 16 + p;
    const float* pw = w + ((size_t)oc * IN_CH + ic) * 9;
    float sum = 0.f;
    #pragma unroll
    for (int t = 0; t < 9; ++t) {
      float v = pw[t];
      sum += v * v;
      wgp[((size_t)((t * 8 + chunk) * 2 + octile) * 2048 + u) * 8 + e] = (__bf16)v;
    }
    wsq[oc * IN_CH + ic] = sum;
  }
}

// ---------------- fused prepass B: X prep (blocks 0..511) | demod scale (512..575) ------
// xgp unit u=(c,p): col=2c+(p&1) (0..65, data x=col-1), slot s=((p>>1)-c)&7.
// Read: pos=(col&1)+2((s+c)&7); col-local key -> ptile-independent.
__global__ void k_prepB(const float* __restrict__ x, const float* __restrict__ s,
                        const float* __restrict__ wsq,
                        __bf16* __restrict__ xgp, float* __restrict__ scale) {
  const int t = threadIdx.x;
  if (blockIdx.x < 512) {
    const int b = blockIdx.x >> 6, y = blockIdx.x & 63;
    const int xcol = t & 63;          // image x, data col = xcol+1
    const int g0 = t >> 6;            // 0..7
    const float* sr = s + b * IN_CH;
    const size_t rowbase = ((size_t)(b * 64 + y)) * 8 * 528;
    #pragma unroll
    for (int i = 0; i < 8; ++i) {
      const int g = i * 8 + g0;       // chunk*8 + slot
      bf16x8 pk;
      #pragma unroll
      for (int e = 0; e < 8; ++e) {
        const int ic = g * 8 + e;
        pk[e] = (__bf16)(x[(((size_t)(b * IN_CH) + ic) * HW + y) * HW + xcol] * sr[ic]);
      }
      const int col = xcol + 1, c = col >> 1;
      const int p = 2 * (((g & 7) + c) & 7) + (col & 1);
      const int u = c * 16 + p;
      *(bf16x8*)(xgp + (rowbase + (size_t)(g >> 3) * 528 + u) * 8) = pk;
    }
    if (t < 128) {                    // halo cols 0 and 65 -> zeros
      const int col = (t & 1) * 65, g = t >> 1;
      const int c = col >> 1;
      const int p = 2 * (((g & 7) + c) & 7) + (col & 1);
      const int u = c * 16 + p;
      bf16x8 z = {};
      *(bf16x8*)(xgp + (rowbase + (size_t)(g >> 3) * 528 + u) * 8) = z;
    }
  } else {
    const int oc = (blockIdx.x - 512) * 8 + (t >> 6);
    const int l = t & 63;
    const float* wr = wsq + (size_t)oc * IN_CH + l * 8;
    float w8[8];
    #pragma unroll
    for (int j = 0; j < 8; ++j) w8[j] = wr[j];
    #pragma unroll
    for (int b = 0; b < 8; ++b) {
      const float* sb = s + b * IN_CH + l * 8;
      float acc = 0.f;
      #pragma unroll
      for (int j = 0; j < 8; ++j) { float sv = sb[j]; acc += sv * sv * w8[j]; }
      #pragma unroll
      for (int off = 32; off; off >>= 1) acc += __shfl_down(acc, off, 64);
      if (l == 0)
        scale[b * OUT_CH + oc] =
            rsqrtf(acc * (1.0f / 4608.0f) + 1e-8f) * 0.014731391274719732f;
    }
  }
}

// ---------------- main conv: r13 structure, setprio removed ------------------------------
// Conflict-free stripe LDS + coalesced staging (r13-verified). Scheduler left free to
// interleave ds_reads with MFMAs (setprio removal: m190 lockstep-GEMM evidence).
__global__ __launch_bounds__(512, 2) void k_conv(
    const __bf16* __restrict__ Wgp,  // [9][8][2][2048*8]
    const __bf16* __restrict__ Xgp,  // [8][64][8][528*8]
    const float* __restrict__ scale, // [8][512] = demod*cs
    const __bf16* __restrict__ zpg,  // zeros (OOR-row source)
    float* __restrict__ out)         // [8][512][64][64]
{
  __shared__ __attribute__((aligned(16))) __bf16 Xs[3584 * 8];     // 57344 B
  __shared__ __attribute__((aligned(16))) __bf16 Wl[3][2048 * 8];  // 98304 B

  const int tid = threadIdx.x;
  const int lane = tid & 63;
  const int wid = tid >> 6;
  const int wm = wid >> 2;
  const int wn = wid & 3;
  const int ln31 = lane & 31;
  const int laneK = lane >> 5;

  const int bid0 = blockIdx.x;
  const int bid = (bid0 & 7) * 32 + (bid0 >> 3);   // XCD-chunked swizzle
  const int octile = bid & 1;
  const int ptile = (bid >> 1) & 15;
  const int b = bid >> 5;
  const int r0 = ptile * 4;
  const int oc0 = octile * 256;

  auto stage_w = [&](int chunkv, int tapv, int bsel) {  // 4 units/thread, linear
    const __bf16* base = Wgp + (size_t)((tapv * 8 + chunkv) * 2 + octile) * (2048 * 8);
    #pragma unroll
    for (int i = 0; i < 4; ++i) {
      const int u = i * 512 + tid;
      gload_lds16(base + (size_t)u * 8, (void*)((char*)Wl[bsel] + u * 16));
    }
  };
  auto stage_x = [&](int chunkv) {   // 7 units/thread, linear within each row
    #pragma unroll
    for (int i = 0; i < 7; ++i) {
      const unsigned u = i * 512 + tid;
      const unsigned row = u / 528u;            // 0..6 (row 6 = pad)
      const unsigned rr = u - row * 528u;
      const int y = r0 - 1 + (int)row;
      const bool ok = (u < 3168u) & (y >= 0) & (y < HW);
      const __bf16* src = ok
          ? Xgp + (((size_t)(b * 64 + y) * 8 + chunkv) * 528 + rr) * 8
          : zpg;
      gload_lds16(src, (void*)((char*)Xs + u * 16));
    }
  };

  // prologue
  stage_x(0);               // X0(7)
  stage_w(0, 0, 0);         // +W0(4)
  stage_w(0, 1, 1);         // +W1(4) -> first tap's WAITV(4) drains X0+W0, keeps W1

  // ---- read addressing (loop-invariant, const-indexed) ----
  int aoff8[4];
  #pragma unroll
  for (int ks = 0; ks < 4; ++ks) aoff8[ks] = ((ln31 + 4 * ks + 2 * laneK) & 15) * 8;
  int bele[3][4];
  #pragma unroll
  for (int dxi = 0; dxi < 3; ++dxi) {
    const int col = ln31 + dxi, c = col >> 1;
    #pragma unroll
    for (int ks = 0; ks < 4; ++ks) {
      const int pos = (col & 1) + 2 * ((2 * ks + laneK + c) & 7);
      bele[dxi][ks] = c * 128 + pos * 8;
    }
  }
  const __bf16* __restrict__ ab0 = Wl[0] + (64 * wm + (ln31 >> 1)) * 128;
  const __bf16* __restrict__ ab1 = Wl[1] + (64 * wm + (ln31 >> 1)) * 128;
  const __bf16* __restrict__ ab2 = Wl[2] + (64 * wm + (ln31 >> 1)) * 128;

  f32x16 acc[4][2] = {};

#define TAPBODY(T) { \
    if ((T) == 8 && c == 7) { WAITV(0); } else { WAITV(4); } \
    BARRIER(); \
    const __bf16* __restrict__ abase = ((T) % 3 == 0) ? ab0 : ((T) % 3 == 1) ? ab1 : ab2; \
    const __bf16* __restrict__ xbase = Xs + (wn + (T) / 3) * (33 * 128); \
    _Pragma("unroll") \
    for (int ks = 0; ks < 4; ++ks) { \
      const int ael = aoff8[ks]; \
      const int bel = bele[(T) % 3][ks]; \
      bf16x8 av[4], bv[2]; \
      _Pragma("unroll") \
      for (int mf = 0; mf < 4; ++mf) av[mf] = *(const bf16x8*)(abase + mf * 2048 + ael); \
      bv[0] = *(const bf16x8*)(xbase + bel); \
      bv[1] = *(const bf16x8*)(xbase + 2048 + bel); \
      _Pragma("unroll") \
      for (int mf = 0; mf < 4; ++mf) { \
        acc[mf][0] = __builtin_amdgcn_mfma_f32_32x32x16_bf16(av[mf], bv[0], acc[mf][0], 0, 0, 0); \
        acc[mf][1] = __builtin_amdgcn_mfma_f32_32x32x16_bf16(av[mf], bv[1], acc[mf][1], 0, 0, 0); \
      } \
    } \
    if ((T) == 8) { \
      if (c < 7) { BARRIER(); stage_x(c + 1); stage_w(c + 1, 1, 1); } \
    } else if ((T) <= 6) { \
      stage_w(c, (T) + 2, ((T) + 2) % 3); \
    } else { /* T == 7 */ \
      if (c < 7) stage_w(c + 1, 0, 0); \
    } \
  }

  #pragma unroll 1
  for (int c = 0; c < 8; ++c) {
    TAPBODY(0) TAPBODY(1) TAPBODY(2)
    TAPBODY(3) TAPBODY(4) TAPBODY(5)
    TAPBODY(6) TAPBODY(7) TAPBODY(8)
  }

  // epilogue: out = acc * (demod*cs), NCHW
  const int y = r0 + wn;
  #pragma unroll
  for (int mf = 0; mf < 4; ++mf) {
    #pragma unroll
    for (int reg = 0; reg < 16; ++reg) {
      const int rowid = (reg & 3) + 8 * (reg >> 2) + 4 * laneK;
      const int oc = oc0 + 128 * wm + 32 * mf + rowid;
      const float sc = scale[b * OUT_CH + oc];
      float* op = out + (((size_t)(b * OUT_CH + oc) * HW + y) * HW) + ln31;
      op[0] = acc[mf][0][reg] * sc;
      op[32] = acc[mf][1][reg] * sc;
    }
  }
}

// ---------------- launcher ---------------------------------------------------------------
extern "C" void kernel_launch(void* const* d_in, const int* in_sizes, int n_in,
                              void* d_out, int out_size, void* d_ws, size_t ws_size,
                              hipStream_t stream) {
  const float* x      = (const float*)d_in[0];
  const float* style  = (const float*)d_in[1];
  const float* weight = (const float*)d_in[2];
  const float* modw   = (const float*)d_in[3];
  const float* modb   = (const float*)d_in[4];
  float* out = (float*)d_out;

  char* ws = (char*)d_ws;
  float*  s_buf = (float*)(ws + 0);                        // 16 KB
  float*  scale = (float*)(ws + 16384);                    // 16 KB
  __bf16* zpg   = (__bf16*)(ws + 32768);                   // 16 KB zero page
  float*  wsq   = (float*)(ws + 49152);                    // 1 MB
  __bf16* wgp   = (__bf16*)(ws + 49152 + 1048576);         // 4.72 MB
  __bf16* xgp   = (__bf16*)(ws + 49152 + 1048576 + 9 * 8 * 2 * 2048 * 8 * 2);  // 34.6 MB

  hipMemsetAsync(zpg, 0, 16384, stream);
  k_prepA<<<1152, 256, 0, stream>>>(style, modw, modb, weight, s_buf, wsq, wgp);
  k_prepB<<<576, 512, 0, stream>>>(x, s_buf, wsq, xgp, scale);
  k_conv<<<256, 512, 0, stream>>>(wgp, xgp, scale, zpg, out);
}

// Round 15
// 160.500 us; speedup vs baseline: 1.2470x; 1.0051x over previous
//
#include <hip/hip_runtime.h>
#include <hip/hip_bf16.h>
#include <cstdint>

#define IN_CH 512
#define OUT_CH 512
#define STYLE_DIM 512
#define BATCH 8
#define HW 64

typedef __bf16 bf16x8 __attribute__((ext_vector_type(8)));
typedef float f32x16 __attribute__((ext_vector_type(16)));

__device__ __forceinline__ void gload_lds16(const void* g, void* l) {
  __builtin_amdgcn_global_load_lds(
      (const __attribute__((address_space(1))) unsigned int*)g,
      (__attribute__((address_space(3))) unsigned int*)l,
      16, 0, 0);
}

#define WAITV(N) asm volatile("s_waitcnt vmcnt(" #N ")" ::: "memory")
#define BARRIER() do { asm volatile("" ::: "memory"); __builtin_amdgcn_s_barrier(); \
                       asm volatile("" ::: "memory"); } while (0)

// ---------------- kernel 1: style-GEMM (blocks 0..127) | zpg zero (block 128) ------------
__global__ void k_style(const float* __restrict__ style, const float* __restrict__ modw,
                        const float* __restrict__ modb, float* __restrict__ s_out,
                        float* __restrict__ zpg) {
  const int tid = threadIdx.x;
  if (blockIdx.x == 128) {            // zero page for conv OOR-row staging
    float4 z = {0.f, 0.f, 0.f, 0.f};
    #pragma unroll
    for (int k = 0; k < 4; ++k) ((float4*)zpg)[tid * 4 + k] = z;
    return;
  }
  __shared__ float st[BATCH * STYLE_DIM];
  for (int i = tid; i < BATCH * STYLE_DIM; i += 256) st[i] = style[i];
  __syncthreads();
  const int ic = blockIdx.x * 4 + (tid >> 6);
  const int l = tid & 63;
  const float* mr = modw + (size_t)ic * STYLE_DIM + l * 8;
  float m[8];
  #pragma unroll
  for (int j = 0; j < 8; ++j) m[j] = mr[j];
  float accs[8];
  #pragma unroll
  for (int b = 0; b < 8; ++b) {
    const float* sb = st + b * STYLE_DIM + l * 8;
    float a = 0.f;
    #pragma unroll
    for (int j = 0; j < 8; ++j) a += m[j] * sb[j];
    accs[b] = a;
  }
  #pragma unroll
  for (int off = 32; off; off >>= 1) {
    #pragma unroll
    for (int b = 0; b < 8; ++b) accs[b] += __shfl_down(accs[b], off, 64);
  }
  if (l == 0) {
    #pragma unroll
    for (int b = 0; b < 8; ++b)
      s_out[b * IN_CH + ic] = accs[b] * 0.04419417382415922f + modb[ic];
  }
}

// ---------------- kernel 2 (fused, depends only on s_buf/x/w): -------------------------
// blocks 0..511: xprep | 512..1023: wprep (stripe layout) | 1024..1087: demod-direct
__global__ void k_prep(const float* __restrict__ x, const float* __restrict__ s,
                       const float* __restrict__ w,
                       __bf16* __restrict__ xgp, __bf16* __restrict__ wgp,
                       float* __restrict__ scale) {
  const int t = threadIdx.x;
  const int bid = blockIdx.x;
  if (bid < 512) {
    // xgp unit u=(c,p): col=2c+(p&1), slot s=((p>>1)-c)&7; read pos=(col&1)+2((s+c)&7)
    const int b = bid >> 6, y = bid & 63;
    const int xcol = t & 63;
    const int g0 = t >> 6;
    const float* sr = s + b * IN_CH;
    const size_t rowbase = ((size_t)(b * 64 + y)) * 8 * 528;
    #pragma unroll
    for (int i = 0; i < 8; ++i) {
      const int g = i * 8 + g0;
      bf16x8 pk;
      #pragma unroll
      for (int e = 0; e < 8; ++e) {
        const int ic = g * 8 + e;
        pk[e] = (__bf16)(x[(((size_t)(b * IN_CH) + ic) * HW + y) * HW + xcol] * sr[ic]);
      }
      const int col = xcol + 1, c = col >> 1;
      const int p = 2 * (((g & 7) + c) & 7) + (col & 1);
      *(bf16x8*)(xgp + (rowbase + (size_t)(g >> 3) * 528 + c * 16 + p) * 8) = pk;
    }
    if (t < 128) {                    // halo cols 0 and 65 -> zeros
      const int col = (t & 1) * 65, g = t >> 1;
      const int c = col >> 1;
      const int p = 2 * (((g & 7) + c) & 7) + (col & 1);
      bf16x8 z = {};
      *(bf16x8*)(xgp + (rowbase + (size_t)(g >> 3) * 528 + c * 16 + p) * 8) = z;
    }
  } else if (bid < 1024) {
    // wgp[tap][chunk][octile][2048u]; u=(j,p): R=2j+(p&1), s=((p>>1)-j)&7
    const int idx = (bid - 512) * 512 + t;   // 262144
    const int oc = idx >> 9, ic = idx & 511;
    const int octile = oc >> 8, R = oc & 255, j = R >> 1;
    const int chunk = ic >> 6, sslot = (ic >> 3) & 7, e = ic & 7;
    const int p = 2 * ((sslot + j) & 7) + (R & 1);
    const int u = j * 16 + p;
    const float* pw = w + ((size_t)oc * IN_CH + ic) * 9;
    #pragma unroll
    for (int tp = 0; tp < 9; ++tp)
      wgp[((size_t)((tp * 8 + chunk) * 2 + octile) * 2048 + u) * 8 + e] = (__bf16)pw[tp];
  } else {
    // demod-direct: scale[b][oc] = rsqrt(sum(s^2 * sum_t W^2)/4608 + eps) * cs
    const int oc = (bid - 1024) * 8 + (t >> 6);
    const int l = t & 63;
    float w8[8];
    #pragma unroll
    for (int j = 0; j < 8; ++j) {
      const float* pw = w + ((size_t)oc * IN_CH + l * 8 + j) * 9;
      float sum = 0.f;
      #pragma unroll
      for (int tp = 0; tp < 9; ++tp) { float v = pw[tp]; sum += v * v; }
      w8[j] = sum;
    }
    #pragma unroll
    for (int b = 0; b < 8; ++b) {
      const float* sb = s + b * IN_CH + l * 8;
      float acc = 0.f;
      #pragma unroll
      for (int j = 0; j < 8; ++j) { float sv = sb[j]; acc += sv * sv * w8[j]; }
      #pragma unroll
      for (int off = 32; off; off >>= 1) acc += __shfl_down(acc, off, 64);
      if (l == 0)
        scale[b * OUT_CH + oc] =
            rsqrtf(acc * (1.0f / 4608.0f) + 1e-8f) * 0.014731391274719732f;
    }
  }
}

// ---------------- main conv: r14 + ks stagger + next-tap bv prefetch ---------------------
// Stagger: wave starts its ks sweep at kord=wid&3 (fold into offsets; accumulation
// commutes) -> waves' read/MFMA bursts desync. Prefetch: end of tap T reads tap T+1's
// first-ks B fragments (Xs stable within chunk; 16 spare VGPRs) -> post-barrier first
// MFMA waits on 4 A-reads instead of 6.
__global__ __launch_bounds__(512, 2) void k_conv(
    const __bf16* __restrict__ Wgp,  // [9][8][2][2048*8]
    const __bf16* __restrict__ Xgp,  // [8][64][8][528*8]
    const float* __restrict__ scale, // [8][512] = demod*cs
    const __bf16* __restrict__ zpg,  // zeros (OOR-row source)
    float* __restrict__ out)         // [8][512][64][64]
{
  __shared__ __attribute__((aligned(16))) __bf16 Xs[3584 * 8];     // 57344 B
  __shared__ __attribute__((aligned(16))) __bf16 Wl[3][2048 * 8];  // 98304 B

  const int tid = threadIdx.x;
  const int lane = tid & 63;
  const int wid = tid >> 6;
  const int wm = wid >> 2;
  const int wn = wid & 3;
  const int ln31 = lane & 31;
  const int laneK = lane >> 5;
  const int kord = wid & 3;     // ks-phase stagger

  const int bid0 = blockIdx.x;
  const int bid = (bid0 & 7) * 32 + (bid0 >> 3);   // XCD-chunked swizzle
  const int octile = bid & 1;
  const int ptile = (bid >> 1) & 15;
  const int b = bid >> 5;
  const int r0 = ptile * 4;
  const int oc0 = octile * 256;

  auto stage_w = [&](int chunkv, int tapv, int bsel) {
    const __bf16* base = Wgp + (size_t)((tapv * 8 + chunkv) * 2 + octile) * (2048 * 8);
    #pragma unroll
    for (int i = 0; i < 4; ++i) {
      const int u = i * 512 + tid;
      gload_lds16(base + (size_t)u * 8, (void*)((char*)Wl[bsel] + u * 16));
    }
  };
  auto stage_x = [&](int chunkv) {
    #pragma unroll
    for (int i = 0; i < 7; ++i) {
      const unsigned u = i * 512 + tid;
      const unsigned row = u / 528u;
      const unsigned rr = u - row * 528u;
      const int y = r0 - 1 + (int)row;
      const bool ok = (u < 3168u) & (y >= 0) & (y < HW);
      const __bf16* src = ok
          ? Xgp + (((size_t)(b * 64 + y) * 8 + chunkv) * 528 + rr) * 8
          : zpg;
      gload_lds16(src, (void*)((char*)Xs + u * 16));
    }
  };

  // prologue
  stage_x(0);
  stage_w(0, 0, 0);
  stage_w(0, 1, 1);

  // ---- read addressing with kord folded in (const-indexed by unroll var i) ----
  int aoffR[4];
  #pragma unroll
  for (int i = 0; i < 4; ++i)
    aoffR[i] = ((ln31 + 4 * (kord + i) + 2 * laneK) & 15) * 8;
  int beleR[3][4];
  #pragma unroll
  for (int dxi = 0; dxi < 3; ++dxi) {
    const int col = ln31 + dxi, c = col >> 1;
    #pragma unroll
    for (int i = 0; i < 4; ++i) {
      const int pos = (col & 1) + 2 * ((2 * (kord + i) + laneK + c) & 7);
      beleR[dxi][i] = c * 128 + pos * 8;
    }
  }
  const __bf16* __restrict__ ab0 = Wl[0] + (64 * wm + (ln31 >> 1)) * 128;
  const __bf16* __restrict__ ab1 = Wl[1] + (64 * wm + (ln31 >> 1)) * 128;
  const __bf16* __restrict__ ab2 = Wl[2] + (64 * wm + (ln31 >> 1)) * 128;

  f32x16 acc[4][2] = {};
  bf16x8 bvp0, bvp1;   // next-tap first-ks B prefetch (16 VGPR)

#define TAPBODY(T) { \
    if ((T) == 8 && c == 7) { WAITV(0); } else { WAITV(4); } \
    BARRIER(); \
    const __bf16* __restrict__ abase = ((T) % 3 == 0) ? ab0 : ((T) % 3 == 1) ? ab1 : ab2; \
    const __bf16* __restrict__ xbase = Xs + (wn + (T) / 3) * (33 * 128); \
    _Pragma("unroll") \
    for (int i = 0; i < 4; ++i) { \
      const int ael = aoffR[i]; \
      const int bel = beleR[(T) % 3][i]; \
      bf16x8 av[4], bv[2]; \
      _Pragma("unroll") \
      for (int mf = 0; mf < 4; ++mf) av[mf] = *(const bf16x8*)(abase + mf * 2048 + ael); \
      if ((T) > 0 && i == 0) { bv[0] = bvp0; bv[1] = bvp1; } \
      else { bv[0] = *(const bf16x8*)(xbase + bel); \
             bv[1] = *(const bf16x8*)(xbase + 2048 + bel); } \
      _Pragma("unroll") \
      for (int mf = 0; mf < 4; ++mf) { \
        acc[mf][0] = __builtin_amdgcn_mfma_f32_32x32x16_bf16(av[mf], bv[0], acc[mf][0], 0, 0, 0); \
        acc[mf][1] = __builtin_amdgcn_mfma_f32_32x32x16_bf16(av[mf], bv[1], acc[mf][1], 0, 0, 0); \
      } \
    } \
    if ((T) < 8) {   /* prefetch tap T+1's first-ks B (Xs stable within chunk) */ \
      const __bf16* __restrict__ xn = Xs + (wn + ((T) + 1) / 3) * (33 * 128); \
      const int beln = beleR[((T) + 1) % 3][0]; \
      bvp0 = *(const bf16x8*)(xn + beln); \
      bvp1 = *(const bf16x8*)(xn + 2048 + beln); \
    } \
    if ((T) == 8) { \
      if (c < 7) { BARRIER(); stage_x(c + 1); stage_w(c + 1, 1, 1); } \
    } else if ((T) <= 6) { \
      stage_w(c, (T) + 2, ((T) + 2) % 3); \
    } else { /* T == 7 */ \
      if (c < 7) stage_w(c + 1, 0, 0); \
    } \
  }

  #pragma unroll 1
  for (int c = 0; c < 8; ++c) {
    TAPBODY(0) TAPBODY(1) TAPBODY(2)
    TAPBODY(3) TAPBODY(4) TAPBODY(5)
    TAPBODY(6) TAPBODY(7) TAPBODY(8)
  }

  // epilogue: out = acc * (demod*cs), NCHW
  const int y = r0 + wn;
  #pragma unroll
  for (int mf = 0; mf < 4; ++mf) {
    #pragma unroll
    for (int reg = 0; reg < 16; ++reg) {
      const int rowid = (reg & 3) + 8 * (reg >> 2) + 4 * laneK;
      const int oc = oc0 + 128 * wm + 32 * mf + rowid;
      const float sc = scale[b * OUT_CH + oc];
      float* op = out + (((size_t)(b * OUT_CH + oc) * HW + y) * HW) + ln31;
      op[0] = acc[mf][0][reg] * sc;
      op[32] = acc[mf][1][reg] * sc;
    }
  }
}

// ---------------- launcher ---------------------------------------------------------------
extern "C" void kernel_launch(void* const* d_in, const int* in_sizes, int n_in,
                              void* d_out, int out_size, void* d_ws, size_t ws_size,
                              hipStream_t stream) {
  const float* x      = (const float*)d_in[0];
  const float* style  = (const float*)d_in[1];
  const float* weight = (const float*)d_in[2];
  const float* modw   = (const float*)d_in[3];
  const float* modb   = (const float*)d_in[4];
  float* out = (float*)d_out;

  char* ws = (char*)d_ws;
  float*  s_buf = (float*)(ws + 0);                        // 16 KB
  float*  scale = (float*)(ws + 16384);                    // 16 KB
  __bf16* zpg   = (__bf16*)(ws + 32768);                   // 16 KB zero page
  __bf16* wgp   = (__bf16*)(ws + 49152);                   // 4.72 MB
  __bf16* xgp   = (__bf16*)(ws + 49152 + 9 * 8 * 2 * 2048 * 8 * 2);  // 34.6 MB

  k_style<<<129, 256, 0, stream>>>(style, modw, modb, s_buf, (float*)zpg);
  k_prep<<<1088, 512, 0, stream>>>(x, s_buf, weight, xgp, wgp, scale);
  k_conv<<<256, 512, 0, stream>>>(wgp, xgp, scale, zpg, out);
}